// Round 17
// baseline (739.155 us; speedup 1.0000x reference)
//
#include <hip/hip_runtime.h>
#include <hip/hip_bf16.h>
#include <hip/hip_fp16.h>

// Problem constants
#define Bb 256
#define Nn_ 17
#define CIN 3
#define HID 64
#define CCH 128        // HEADS*HID
#define Gg 16384       // B*S
#define Ee 81          // 64 edges + 17 self loops
#define LSTM_IN 2176   // 17*128
#define OUT_ 128
#define G4 512         // 4*OUT
#define NCLS 10
#define Tt 64
#define Mg (Gg * Nn_)  // 278528

typedef unsigned short u16;
typedef unsigned int u32;
typedef __attribute__((ext_vector_type(8))) short bf16x8;
typedef __attribute__((ext_vector_type(4))) float f32x4;
typedef _Float16 h2f __attribute__((ext_vector_type(2)));

__device__ __forceinline__ u16 f2bf(float f) {   // RNE fp32->bf16
    u32 u = __float_as_uint(f);
    u += 0x7fffu + ((u >> 16) & 1u);
    return (u16)(u >> 16);
}
__device__ __forceinline__ float bflo(u32 v) { return __uint_as_float(v << 16); }
__device__ __forceinline__ float bfhi(u32 v) { return __uint_as_float(v & 0xffff0000u); }
__device__ __forceinline__ u16 f2h(float f) {    // RNE fp32->fp16
    _Float16 h = (_Float16)f;
    return *(u16*)&h;
}

// packed half2 dot-accumulate: acc += w.lo*h.lo + w.hi*h.hi
__device__ __forceinline__ float dot2acc(u32 w, u32 h, float acc) {
#if __has_builtin(__builtin_amdgcn_fdot2)
    return __builtin_amdgcn_fdot2(*(h2f*)&w, *(h2f*)&h, acc, false);
#else
    const __half2 wv = *(__half2*)&w, hv = *(__half2*)&h;
    return acc + __half2float(wv.x) * __half2float(hv.x)
               + __half2float(wv.y) * __half2float(hv.y);
#endif
}

__device__ __forceinline__ void async16(const void* g, void* l) {
    __builtin_amdgcn_global_load_lds((__attribute__((address_space(1))) u32*)g,
                                     (__attribute__((address_space(3))) u32*)l, 16, 0, 0);
}

// ---------------- setup: build src/dst + dst-CSR (parallel edge staging)
__global__ __launch_bounds__(128) void k_setup(const int* __restrict__ edge_index,
                                               int* __restrict__ csr) {
    __shared__ int eis[128];
    const int t = threadIdx.x;
    eis[t] = edge_index[t];
    __syncthreads();
    if (t == 0) {
        int* src = csr;                    // [81]
        int* dst = csr + Ee;               // [81]
        int* off = csr + 2 * Ee;           // [18]
        int* eid = csr + 2 * Ee + Nn_ + 1; // [81]
        int s_[Ee], d_[Ee];
        for (int e = 0; e < 64; e++) { s_[e] = eis[e]; d_[e] = eis[64 + e]; }
        for (int n = 0; n < Nn_; n++) { s_[64 + n] = n; d_[64 + n] = n; }
        int cnt[Nn_];
        for (int n = 0; n < Nn_; n++) cnt[n] = 0;
        for (int e = 0; e < Ee; e++) cnt[d_[e]]++;
        int offl[Nn_ + 1];
        offl[0] = 0;
        for (int n = 0; n < Nn_; n++) offl[n + 1] = offl[n] + cnt[n];
        int pos[Nn_];
        for (int n = 0; n < Nn_; n++) pos[n] = offl[n];
        for (int e = 0; e < Ee; e++) { src[e] = s_[e]; dst[e] = d_[e]; }
        for (int n = 0; n <= Nn_; n++) off[n] = offl[n];
        for (int e = 0; e < Ee; e++) eid[pos[d_[e]]++] = e;
    }
}

__global__ void k_convert(const float* __restrict__ in, u16* __restrict__ out, long n) {
    long i = (long)blockIdx.x * 256 + threadIdx.x;
    if (i < n) out[i] = f2bf(in[i]);
}

// ---------------- merged small-weight conversion: 3 transposed GAT weights (bf16),
// wih1 (bf16 for MFMA), whh0/whh1 (f16 for the dot2 recurrence)
__global__ __launch_bounds__(256) void k_convert_small(
    const float* __restrict__ gw1, const float* __restrict__ gw2, const float* __restrict__ gw3,
    const float* __restrict__ wih1, const float* __restrict__ whh0, const float* __restrict__ whh1,
    u16* __restrict__ wt1, u16* __restrict__ wt2, u16* __restrict__ wt3,
    u16* __restrict__ wih1b, u16* __restrict__ whh0h, u16* __restrict__ whh1h) {
    const int i = blockIdx.x * 256 + threadIdx.x;
    if (i < 49152) {
        const int which = i / 16384, r = i % 16384;
        const float* s = (which == 0) ? gw1 : (which == 1) ? gw2 : gw3;
        u16* d = (which == 0) ? wt1 : (which == 1) ? wt2 : wt3;
        const int n = r >> 7, k = r & 127;
        d[r] = f2bf(s[k * 128 + n]);
    } else {
        const int ii = i - 49152;
        const int which = ii / 65536, r = ii % 65536;
        if (which == 0) wih1b[r] = f2bf(wih1[r]);
        else if (which == 1) whh0h[r] = f2h(whh0[r]);
        else whh1h[r] = f2h(whh1[r]);
    }
}

// ---------------- GAT layer 0: h[Mg,128]=x@W0 (bf16) + aux[Mg,4]=x@(W0@a) (fp32)
__global__ __launch_bounds__(256) void k_l0(const float* __restrict__ x,
                                            const float* __restrict__ W0,
                                            const float* __restrict__ gas0,
                                            const float* __restrict__ gad0,
                                            u16* __restrict__ h, float* __restrict__ aux) {
    __shared__ float ws[3 * 128];
    __shared__ float w0a[12];   // [ci][j]  j: src_h0,src_h1,dst_h0,dst_h1
    const int t = threadIdx.x;
    for (int i = t; i < 384; i += 256) ws[i] = W0[i];
    __syncthreads();
    if (t < 12) {
        int ci = t >> 2, j = t & 3;
        const float* a = (j < 2) ? gas0 : gad0;
        int hh = j & 1;
        float s = 0.f;
        for (int d = 0; d < HID; d++) s += ws[ci * 128 + hh * 64 + d] * a[hh * 64 + d];
        w0a[t] = s;
    }
    __syncthreads();
    const long row = (long)blockIdx.x * 16 + (t >> 4);
    const int c0 = (t & 15) * 8;
    const float x0 = x[row * 3 + 0], x1 = x[row * 3 + 1], x2 = x[row * 3 + 2];
    union { uint4 u; u16 s[8]; } o;
#pragma unroll
    for (int j = 0; j < 8; j++)
        o.s[j] = f2bf(x0 * ws[c0 + j] + x1 * ws[128 + c0 + j] + x2 * ws[256 + c0 + j]);
    *(uint4*)(h + row * 128 + c0) = o.u;
    if ((t & 15) < 4) {
        int j = t & 3;
        aux[row * 4 + j] = x0 * w0a[j] + x1 * w0a[4 + j] + x2 * w0a[8 + j];
    }
}

// ---------------- GAT MFMA GEMM (in-place): hbuf = hbuf @ W ; aux = fp32 dots
// r17: 64-row blocks (was 128). r16 PMC showed 63us at Occupancy 26%, VALU 15%,
// MFMA 5%, hbm 22% -- nothing saturated, latency-bound with ~2 blocks/CU. Halving
// the block (16 KB LDS, 1 m-tile/wave, 32 MFMA) doubles resident blocks and
// independent chains. In-place still safe: full output width, row-disjoint 64-row
// slices, A staged to LDS before any write.
__global__ __launch_bounds__(256) void k_gemm_gat(u16* __restrict__ HB,
                                                  const u16* __restrict__ Wt,
                                                  const float* __restrict__ a_src,
                                                  const float* __restrict__ a_dst,
                                                  float* __restrict__ aux) {
    __shared__ u16 ldsA[64 * 128];  // 16 KB
    __shared__ float avec[128], dvec[128];
    const int t = threadIdx.x;
    const int w = t >> 6, lane = t & 63;
    const int q = lane >> 4, col = lane & 15;
    const long bm = (long)blockIdx.x * 64;

    if (t < 128) avec[t] = a_src[t];
    else dvec[t - 128] = a_dst[t - 128];

    // stage A: 1024 chunk-slots of 16B, 4 async16 per thread
#pragma unroll
    for (int i = 0; i < 4; i++) {
        const int slot = (w * 4 + i) * 64 + lane;
        const int r = slot >> 4, cs = slot & 15;
        const int cg = cs ^ (r & 15);
        async16(HB + (bm + r) * 128 + cg * 8, ldsA + slot * 8);
    }
    __syncthreads();

    // wave w owns m-tile w (rows w*16..w*16+15)
    const int rowA = w * 16 + col;
    bf16x8 af[4];
#pragma unroll
    for (int ks = 0; ks < 4; ks++)
        af[ks] = *(const bf16x8*)&ldsA[rowA * 128 + (((ks * 4 + q) ^ (rowA & 15)) << 3)];
    f32x4 acc[8] = {};
#pragma unroll
    for (int ks = 0; ks < 4; ks++)
#pragma unroll
        for (int nt = 0; nt < 8; nt++) {
            bf16x8 bf = *(const bf16x8*)&Wt[(nt * 16 + col) * 128 + (ks * 4 + q) * 8];
            acc[nt] = __builtin_amdgcn_mfma_f32_16x16x32_bf16(af[ks], bf, acc[nt], 0, 0, 0);
        }
    __syncthreads();   // all LDS A-reads done (paranoia before in-place global writes)
#pragma unroll
    for (int nt = 0; nt < 8; nt++) {
        const int cg = nt * 16 + col;
#pragma unroll
        for (int r = 0; r < 4; r++) {
            const long rg = bm + w * 16 + q * 4 + r;
            HB[rg * 128 + cg] = f2bf(acc[nt][r]);
        }
    }
#pragma unroll
    for (int r = 0; r < 4; r++) {
        float s0 = 0.f, s1 = 0.f, d0 = 0.f, d1 = 0.f;
#pragma unroll
        for (int nt = 0; nt < 4; nt++) {
            const float v = acc[nt][r];
            s0 += v * avec[nt * 16 + col];
            d0 += v * dvec[nt * 16 + col];
        }
#pragma unroll
        for (int nt = 4; nt < 8; nt++) {
            const float v = acc[nt][r];
            s1 += v * avec[nt * 16 + col];
            d1 += v * dvec[nt * 16 + col];
        }
#pragma unroll
        for (int o = 1; o < 16; o <<= 1) {
            s0 += __shfl_xor(s0, o);
            s1 += __shfl_xor(s1, o);
            d0 += __shfl_xor(d0, o);
            d1 += __shfl_xor(d1, o);
        }
        if (col == 0) {
            const long rg = bm + w * 16 + q * 4 + r;
            aux[rg * 4 + 0] = s0;
            aux[rg * 4 + 1] = s1;
            aux[rg * 4 + 2] = d0;
            aux[rg * 4 + 3] = d1;
        }
    }
}

// ---------------- GAT attention (4 graphs/block), 16B-vectorized staging + aggregation
#define GPB 4
__global__ __launch_bounds__(256) void k_gat_attn(u16* __restrict__ h,
                                                  const float* __restrict__ aux,
                                                  const float* __restrict__ bias,
                                                  const int* __restrict__ csr,
                                                  int relu_flag) {
    __shared__ __align__(16) u32 hs[GPB * Nn_ * 64];   // [g][n][cp]
    __shared__ float asd[GPB * Nn_ * 4];
    __shared__ float ev[GPB][162];
    __shared__ float mS[GPB][34], dS[GPB][34];
    __shared__ float bvec[128];
    __shared__ int srcS[Ee], dstS[Ee], offS[Nn_ + 1], eidS[Ee];
    const int t = threadIdx.x;
    const long g0 = (long)blockIdx.x * GPB;

    if (t < Ee) { srcS[t] = csr[t]; dstS[t] = csr[Ee + t]; eidS[t] = csr[180 + t]; }
    if (t >= 128 && t < 128 + Nn_ + 1) offS[t - 128] = csr[162 + t - 128];
    if (t < 128) bvec[t] = bias[t];
    {
        const uint4* hg4 = (const uint4*)((const u32*)h + g0 * 1088);
        for (int i = t; i < GPB * Nn_ * 16; i += 256) ((uint4*)hs)[i] = hg4[i];
        const float* ag = aux + g0 * 68;
        for (int i = t; i < GPB * Nn_ * 4; i += 256) asd[i] = ag[i];   // 272 > 256 (r8 bugfix)
    }
    __syncthreads();
    for (int i = t; i < GPB * 162; i += 256) {
        const int g = i / 162, rem = i % 162, e = rem >> 1, hh = rem & 1;
        float v = asd[(g * Nn_ + srcS[e]) * 4 + hh] + asd[(g * Nn_ + dstS[e]) * 4 + 2 + hh];
        ev[g][rem] = (v > 0.f) ? v : 0.2f * v;
    }
    __syncthreads();
    if (t < GPB * 34) {
        const int g = t / 34, rem = t % 34, n = rem >> 1, hh = rem & 1;
        const int p0 = offS[n], p1 = offS[n + 1];
        float m = -1e30f;
        for (int p = p0; p < p1; p++) m = fmaxf(m, ev[g][eidS[p] * 2 + hh]);
        float den = 0.f;
        for (int p = p0; p < p1; p++) den += expf(ev[g][eidS[p] * 2 + hh] - m);
        mS[g][rem] = m;
        dS[g][rem] = den;
    }
    __syncthreads();
    for (int i = t; i < GPB * 162; i += 256) {
        const int g = i / 162, rem = i % 162, e = rem >> 1, hh = rem & 1;
        const int n = dstS[e];
        ev[g][rem] = expf(ev[g][rem] - mS[g][n * 2 + hh]) / (dS[g][n * 2 + hh] + 1e-16f);
    }
    __syncthreads();
    // aggregation: items = (g, n, cq), each covers 8 bf16 columns (one uint4)
    uint4* hgo4 = (uint4*)((u32*)h + g0 * 1088);
    for (int i = t; i < GPB * Nn_ * 16; i += 256) {
        const int g = i / (Nn_ * 16), rem = i % (Nn_ * 16);
        const int n = rem >> 4, cq = rem & 15, hh = cq >> 3;
        const int p0 = offS[n], p1 = offS[n + 1];
        float a[8] = {};
        for (int p = p0; p < p1; p++) {
            const int e = eidS[p];
            const uint4 hv = ((const uint4*)hs)[(g * Nn_ + srcS[e]) * 16 + cq];
            const float al = ev[g][e * 2 + hh];
            a[0] += al * bflo(hv.x); a[1] += al * bfhi(hv.x);
            a[2] += al * bflo(hv.y); a[3] += al * bfhi(hv.y);
            a[4] += al * bflo(hv.z); a[5] += al * bfhi(hv.z);
            a[6] += al * bflo(hv.w); a[7] += al * bfhi(hv.w);
        }
        const int c0 = cq * 8;
#pragma unroll
        for (int m2 = 0; m2 < 8; m2++) {
            a[m2] += bvec[c0 + m2];
            if (relu_flag) a[m2] = fmaxf(a[m2], 0.f);
        }
        uint4 o;
        o.x = (u32)f2bf(a[0]) | ((u32)f2bf(a[1]) << 16);
        o.y = (u32)f2bf(a[2]) | ((u32)f2bf(a[3]) << 16);
        o.z = (u32)f2bf(a[4]) | ((u32)f2bf(a[5]) << 16);
        o.w = (u32)f2bf(a[6]) | ((u32)f2bf(a[7]) << 16);
        hgo4[(g * Nn_ + n) * 16 + cq] = o;
    }
}

// ---------------- bf16 MFMA GEMM: C[M,ldc] = A[M,K]bf16 @ Bt[N,K]bf16^T + b1[n]+b2[n] (fp32)
__global__ __launch_bounds__(256) void k_gemm_mfma(const u16* __restrict__ A,
                                                   const u16* __restrict__ Bt,
                                                   float* __restrict__ Cm,
                                                   const float* __restrict__ b1,
                                                   const float* __restrict__ b2,
                                                   int K, int ldc) {
    __shared__ u16 ldsA[128 * 64];
    __shared__ u16 ldsB[128 * 64];
    const int w = threadIdx.x >> 6;
    const int lane = threadIdx.x & 63;
    const long bm = (long)blockIdx.x * 128;
    const int bn = blockIdx.y * 128;
    const int wm = (w & 1) * 64, wn = (w >> 1) * 64;
    const int q = lane >> 4, col = lane & 15;
    f32x4 acc[4][4] = {};
    for (int k0 = 0; k0 < K; k0 += 64) {
#pragma unroll
        for (int i = 0; i < 4; i++) {
            const int slot = (w * 4 + i) * 64 + lane;
            const int r = slot >> 3, cs = slot & 7;
            const int cg = cs ^ (r & 7);
            async16(A + (bm + r) * (long)K + k0 + cg * 8, ldsA + (w * 4 + i) * 512);
            async16(Bt + (long)(bn + r) * K + k0 + cg * 8, ldsB + (w * 4 + i) * 512);
        }
        __syncthreads();
#pragma unroll
        for (int kk = 0; kk < 2; kk++) {
            bf16x8 af[4], bfr[4];
#pragma unroll
            for (int mt = 0; mt < 4; mt++) {
                const int m = wm + mt * 16 + col;
                const int cs = (kk * 4 + q) ^ (m & 7);
                af[mt] = *(const bf16x8*)&ldsA[m * 64 + cs * 8];
            }
#pragma unroll
            for (int nt = 0; nt < 4; nt++) {
                const int n = wn + nt * 16 + col;
                const int cs = (kk * 4 + q) ^ (n & 7);
                bfr[nt] = *(const bf16x8*)&ldsB[n * 64 + cs * 8];
            }
#pragma unroll
            for (int mt = 0; mt < 4; mt++)
#pragma unroll
                for (int nt = 0; nt < 4; nt++)
                    acc[mt][nt] = __builtin_amdgcn_mfma_f32_16x16x32_bf16(af[mt], bfr[nt], acc[mt][nt], 0, 0, 0);
        }
        __syncthreads();
    }
#pragma unroll
    for (int mt = 0; mt < 4; mt++)
#pragma unroll
        for (int nt = 0; nt < 4; nt++) {
            const int cg = bn + wn + nt * 16 + col;
            const float bb = b1[cg] + b2[cg];
#pragma unroll
            for (int r = 0; r < 4; r++) {
                const long rg = bm + wm + mt * 16 + q * 4 + r;
                Cm[rg * ldc + cg] = acc[mt][nt][r] + bb;
            }
        }
}

// ---------------- LSTM recurrence: f16 packed whh + v_dot2_f32_f16 MAC
template <int OBF16>
__global__ __launch_bounds__(512, 1) void k_lstm(const float* __restrict__ XW,
                                                 const u16* __restrict__ whhh,
                                                 void* __restrict__ hseq) {
    const int b = blockIdx.x, j = threadIdx.x;
    u32 wp[64];   // 128 f16 = 64 VGPRs (register-resident at this footprint)
    const u32* wrow = (const u32*)(whhh + (long)j * OUT_);
#pragma unroll
    for (int k = 0; k < 64; k++) wp[k] = wrow[k];
    __shared__ __align__(16) u16 h_sh[OUT_];   // packed f16 h-state (64 u32)
    __shared__ float gate_s[G4];
    float c_r = 0.f;
    if (j < 64) ((u32*)h_sh)[j] = 0;
    float xw = XW[((long)b * Tt + 0) * G4 + j];
    const int gate = j >> 7;   // 0:i 1:f 2:g 3:o
    __syncthreads();
    for (int t = 0; t < Tt; t++) {
        float xw_next = 0.f;
        if (t < Tt - 1) xw_next = XW[((long)b * Tt + t + 1) * G4 + j];
        float a0 = xw, a1 = 0.f, a2 = 0.f, a3 = 0.f;
        const uint4* hv4 = (const uint4*)h_sh;
#pragma unroll
        for (int k = 0; k < 4; k++) {
            const uint4 H0 = hv4[k], H1 = hv4[4 + k], H2 = hv4[8 + k], H3 = hv4[12 + k];
            a0 = dot2acc(wp[4 * k + 0], H0.x, a0);
            a0 = dot2acc(wp[4 * k + 1], H0.y, a0);
            a0 = dot2acc(wp[4 * k + 2], H0.z, a0);
            a0 = dot2acc(wp[4 * k + 3], H0.w, a0);
            a1 = dot2acc(wp[16 + 4 * k + 0], H1.x, a1);
            a1 = dot2acc(wp[16 + 4 * k + 1], H1.y, a1);
            a1 = dot2acc(wp[16 + 4 * k + 2], H1.z, a1);
            a1 = dot2acc(wp[16 + 4 * k + 3], H1.w, a1);
            a2 = dot2acc(wp[32 + 4 * k + 0], H2.x, a2);
            a2 = dot2acc(wp[32 + 4 * k + 1], H2.y, a2);
            a2 = dot2acc(wp[32 + 4 * k + 2], H2.z, a2);
            a2 = dot2acc(wp[32 + 4 * k + 3], H2.w, a2);
            a3 = dot2acc(wp[48 + 4 * k + 0], H3.x, a3);
            a3 = dot2acc(wp[48 + 4 * k + 1], H3.y, a3);
            a3 = dot2acc(wp[48 + 4 * k + 2], H3.z, a3);
            a3 = dot2acc(wp[48 + 4 * k + 3], H3.w, a3);
        }
        const float acc = (a0 + a1) + (a2 + a3);
        gate_s[j] = (gate == 2) ? tanhf(acc) : 1.f / (1.f + expf(-acc));
        __syncthreads();
        if (j < OUT_) {
            const float si = gate_s[j], sf = gate_s[OUT_ + j];
            const float gg = gate_s[2 * OUT_ + j], so = gate_s[3 * OUT_ + j];
            const float c = sf * c_r + si * gg;
            c_r = c;
            const float hh = so * tanhf(c);
            h_sh[j] = f2h(hh);
            const long idx = ((long)b * Tt + t) * OUT_ + j;
            if (OBF16) ((u16*)hseq)[idx] = f2bf(hh);
            else       ((float*)hseq)[idx] = hh;
        }
        xw = xw_next;
        __syncthreads();
    }
}

// ---------------- attention pooling + FC
__global__ __launch_bounds__(64) void k_attn_fc(const float* __restrict__ h2,
                                                const float* __restrict__ attn_w,
                                                const float* __restrict__ attn_b,
                                                const float* __restrict__ fc_w,
                                                const float* __restrict__ fc_b,
                                                float* __restrict__ out) {
    const int b = blockIdx.x, t = threadIdx.x;
    __shared__ float aw[Tt];
    __shared__ float ctx[OUT_];
    const float* hb = h2 + (long)b * Tt * OUT_;
    float acc = 0.f;
    for (int d = 0; d < OUT_; d++) acc += hb[t * OUT_ + d] * attn_w[d];
    float sc = tanhf(acc + attn_b[0]);
    float m = sc;
#pragma unroll
    for (int o = 32; o > 0; o >>= 1) m = fmaxf(m, __shfl_xor(m, o));
    float ex = expf(sc - m);
    float sum = ex;
#pragma unroll
    for (int o = 32; o > 0; o >>= 1) sum += __shfl_xor(sum, o);
    aw[t] = ex / sum;
    __syncthreads();
    for (int d = t; d < OUT_; d += 64) {
        float c = 0.f;
        for (int tt = 0; tt < Tt; tt++) c += aw[tt] * hb[tt * OUT_ + d];
        ctx[d] = c;
    }
    __syncthreads();
    if (t < NCLS) {
        float o = fc_b[t];
        for (int d = 0; d < OUT_; d++) o += ctx[d] * fc_w[t * OUT_ + d];
        out[b * NCLS + t] = o;
    }
}

extern "C" void kernel_launch(void* const* d_in, const int* in_sizes, int n_in,
                              void* d_out, int out_size, void* d_ws, size_t ws_size,
                              hipStream_t stream) {
    const float* x          = (const float*)d_in[0];
    const int*   edge_index = (const int*)d_in[1];
    const float* gw[4]  = {(const float*)d_in[2], (const float*)d_in[6], (const float*)d_in[10], (const float*)d_in[14]};
    const float* gas[4] = {(const float*)d_in[3], (const float*)d_in[7], (const float*)d_in[11], (const float*)d_in[15]};
    const float* gad[4] = {(const float*)d_in[4], (const float*)d_in[8], (const float*)d_in[12], (const float*)d_in[16]};
    const float* gb[4]  = {(const float*)d_in[5], (const float*)d_in[9], (const float*)d_in[13], (const float*)d_in[17]};
    const float* wih0 = (const float*)d_in[18];
    const float* whh0 = (const float*)d_in[19];
    const float* bih0 = (const float*)d_in[20];
    const float* bhh0 = (const float*)d_in[21];
    const float* wih1 = (const float*)d_in[22];
    const float* whh1 = (const float*)d_in[23];
    const float* bih1 = (const float*)d_in[24];
    const float* bhh1 = (const float*)d_in[25];
    const float* attn_w = (const float*)d_in[26];
    const float* attn_b = (const float*)d_in[27];
    const float* fc_w   = (const float*)d_in[28];
    const float* fc_b   = (const float*)d_in[29];
    float* out = (float*)d_out;
    char* p = (char*)d_ws;

    // Workspace (~158.2 MB; 176.2 MB proven OK in round 2)
    u16*   hbuf  = (u16*)(p + 0L);              // 71,303,168 B
    float* aux   = (float*)(p + 71303168L);     //  4,456,448 B
    float* XW0   = (float*)(p + 75759616L);     // 33,554,432 B
    float* XW1   = (float*)(p + 109314048L);    // 33,554,432 B
    float* h2s   = (float*)(p + 142868480L);    //  8,388,608 B
    u16*   h1s   = (u16*)(p + 151257088L);      //  4,194,304 B
    u16*   wih0b = (u16*)(p + 155451392L);      //  2,228,224 B
    u16*   wih1b = (u16*)(p + 157679616L);      //    131,072 B
    u16*   whh0h = (u16*)(p + 157810688L);      //    131,072 B  (f16)
    u16*   whh1h = (u16*)(p + 157941760L);      //    131,072 B  (f16)
    u16*   wt1   = (u16*)(p + 158072832L);      //     32,768 B (x3)
    u16*   wt2   = (u16*)(p + 158105600L);
    u16*   wt3   = (u16*)(p + 158138368L);
    int*   csr   = (int*)(p + 158171136L);      //      1,044 B

    k_setup<<<1, 128, 0, stream>>>(edge_index, csr);
    k_convert_small<<<960, 256, 0, stream>>>(gw[1], gw[2], gw[3], wih1, whh0, whh1,
                                             wt1, wt2, wt3, wih1b, whh0h, whh1h);
    k_convert<<<(512 * 2176 + 255) / 256, 256, 0, stream>>>(wih0, wih0b, 512L * 2176);

    // GAT layer 0 projection (+fp32 attn dots) then attention
    k_l0<<<Mg / 16, 256, 0, stream>>>(x, gw[0], gas[0], gad[0], hbuf, aux);
    k_gat_attn<<<Gg / GPB, 256, 0, stream>>>(hbuf, aux, gb[0], csr, 1);
    // layers 1..3: in-place MFMA GEMM (64-row blocks) with fp32 dot epilogue, then attention
    k_gemm_gat<<<Mg / 64, 256, 0, stream>>>(hbuf, wt1, gas[1], gad[1], aux);
    k_gat_attn<<<Gg / GPB, 256, 0, stream>>>(hbuf, aux, gb[1], csr, 0);
    k_gemm_gat<<<Mg / 64, 256, 0, stream>>>(hbuf, wt2, gas[2], gad[2], aux);
    k_gat_attn<<<Gg / GPB, 256, 0, stream>>>(hbuf, aux, gb[2], csr, 1);
    k_gemm_gat<<<Mg / 64, 256, 0, stream>>>(hbuf, wt3, gas[3], gad[3], aux);
    k_gat_attn<<<Gg / GPB, 256, 0, stream>>>(hbuf, aux, gb[3], csr, 0);

    // LSTM layer 0: input GEMM (hbuf == lstm_in [16384,2176] bf16) + dot2 recurrence
    k_gemm_mfma<<<dim3(Gg / 128, 4), 256, 0, stream>>>(hbuf, wih0b, XW0, bih0, bhh0, LSTM_IN, G4);
    k_lstm<1><<<Bb, 512, 0, stream>>>(XW0, whh0h, h1s);
    // LSTM layer 1
    k_gemm_mfma<<<dim3(Gg / 128, 4), 256, 0, stream>>>(h1s, wih1b, XW1, bih1, bhh1, OUT_, G4);
    k_lstm<0><<<Bb, 512, 0, stream>>>(XW1, whh1h, h2s);

    k_attn_fc<<<Bb, 64, 0, stream>>>(h2s, attn_w, attn_b, fc_w, fc_b, out);
}

// Round 18
// 666.176 us; speedup vs baseline: 1.1095x; 1.1095x over previous
//
#include <hip/hip_runtime.h>
#include <hip/hip_bf16.h>
#include <hip/hip_fp16.h>

// Problem constants
#define Bb 256
#define Nn_ 17
#define CIN 3
#define HID 64
#define CCH 128        // HEADS*HID
#define Gg 16384       // B*S
#define Ee 81          // 64 edges + 17 self loops
#define LSTM_IN 2176   // 17*128
#define OUT_ 128
#define G4 512         // 4*OUT
#define NCLS 10
#define Tt 64
#define Mg (Gg * Nn_)  // 278528

typedef unsigned short u16;
typedef unsigned int u32;
typedef __attribute__((ext_vector_type(8))) short bf16x8;
typedef __attribute__((ext_vector_type(4))) float f32x4;
typedef _Float16 h2f __attribute__((ext_vector_type(2)));

__device__ __forceinline__ u16 f2bf(float f) {   // RNE fp32->bf16
    u32 u = __float_as_uint(f);
    u += 0x7fffu + ((u >> 16) & 1u);
    return (u16)(u >> 16);
}
__device__ __forceinline__ float bflo(u32 v) { return __uint_as_float(v << 16); }
__device__ __forceinline__ float bfhi(u32 v) { return __uint_as_float(v & 0xffff0000u); }
__device__ __forceinline__ u16 f2h(float f) {    // RNE fp32->fp16
    _Float16 h = (_Float16)f;
    return *(u16*)&h;
}

// packed half2 dot-accumulate: acc += w.lo*h.lo + w.hi*h.hi
__device__ __forceinline__ float dot2acc(u32 w, u32 h, float acc) {
#if __has_builtin(__builtin_amdgcn_fdot2)
    return __builtin_amdgcn_fdot2(*(h2f*)&w, *(h2f*)&h, acc, false);
#else
    const __half2 wv = *(__half2*)&w, hv = *(__half2*)&h;
    return acc + __half2float(wv.x) * __half2float(hv.x)
               + __half2float(wv.y) * __half2float(hv.y);
#endif
}

__device__ __forceinline__ void async16(const void* g, void* l) {
    __builtin_amdgcn_global_load_lds((__attribute__((address_space(1))) u32*)g,
                                     (__attribute__((address_space(3))) u32*)l, 16, 0, 0);
}

// ---------------- setup: build src/dst + dst-CSR (parallel edge staging)
__global__ __launch_bounds__(128) void k_setup(const int* __restrict__ edge_index,
                                               int* __restrict__ csr) {
    __shared__ int eis[128];
    const int t = threadIdx.x;
    eis[t] = edge_index[t];
    __syncthreads();
    if (t == 0) {
        int* src = csr;                    // [81]
        int* dst = csr + Ee;               // [81]
        int* off = csr + 2 * Ee;           // [18]
        int* eid = csr + 2 * Ee + Nn_ + 1; // [81]
        int s_[Ee], d_[Ee];
        for (int e = 0; e < 64; e++) { s_[e] = eis[e]; d_[e] = eis[64 + e]; }
        for (int n = 0; n < Nn_; n++) { s_[64 + n] = n; d_[64 + n] = n; }
        int cnt[Nn_];
        for (int n = 0; n < Nn_; n++) cnt[n] = 0;
        for (int e = 0; e < Ee; e++) cnt[d_[e]]++;
        int offl[Nn_ + 1];
        offl[0] = 0;
        for (int n = 0; n < Nn_; n++) offl[n + 1] = offl[n] + cnt[n];
        int pos[Nn_];
        for (int n = 0; n < Nn_; n++) pos[n] = offl[n];
        for (int e = 0; e < Ee; e++) { src[e] = s_[e]; dst[e] = d_[e]; }
        for (int n = 0; n <= Nn_; n++) off[n] = offl[n];
        for (int e = 0; e < Ee; e++) eid[pos[d_[e]]++] = e;
    }
}

__global__ void k_convert(const float* __restrict__ in, u16* __restrict__ out, long n) {
    long i = (long)blockIdx.x * 256 + threadIdx.x;
    if (i < n) out[i] = f2bf(in[i]);
}

// ---------------- merged small-weight conversion: 3 transposed GAT weights (bf16),
// wih1 (bf16 for MFMA), whh0/whh1 (f16 for the dot2 recurrence)
__global__ __launch_bounds__(256) void k_convert_small(
    const float* __restrict__ gw1, const float* __restrict__ gw2, const float* __restrict__ gw3,
    const float* __restrict__ wih1, const float* __restrict__ whh0, const float* __restrict__ whh1,
    u16* __restrict__ wt1, u16* __restrict__ wt2, u16* __restrict__ wt3,
    u16* __restrict__ wih1b, u16* __restrict__ whh0h, u16* __restrict__ whh1h) {
    const int i = blockIdx.x * 256 + threadIdx.x;
    if (i < 49152) {
        const int which = i / 16384, r = i % 16384;
        const float* s = (which == 0) ? gw1 : (which == 1) ? gw2 : gw3;
        u16* d = (which == 0) ? wt1 : (which == 1) ? wt2 : wt3;
        const int n = r >> 7, k = r & 127;
        d[r] = f2bf(s[k * 128 + n]);
    } else {
        const int ii = i - 49152;
        const int which = ii / 65536, r = ii % 65536;
        if (which == 0) wih1b[r] = f2bf(wih1[r]);
        else if (which == 1) whh0h[r] = f2h(whh0[r]);
        else whh1h[r] = f2h(whh1[r]);
    }
}

// ---------------- GAT layer 0: h[Mg,128]=x@W0 (bf16) + aux[Mg,4]=x@(W0@a) (fp32)
__global__ __launch_bounds__(256) void k_l0(const float* __restrict__ x,
                                            const float* __restrict__ W0,
                                            const float* __restrict__ gas0,
                                            const float* __restrict__ gad0,
                                            u16* __restrict__ h, float* __restrict__ aux) {
    __shared__ float ws[3 * 128];
    __shared__ float w0a[12];   // [ci][j]  j: src_h0,src_h1,dst_h0,dst_h1
    const int t = threadIdx.x;
    for (int i = t; i < 384; i += 256) ws[i] = W0[i];
    __syncthreads();
    if (t < 12) {
        int ci = t >> 2, j = t & 3;
        const float* a = (j < 2) ? gas0 : gad0;
        int hh = j & 1;
        float s = 0.f;
        for (int d = 0; d < HID; d++) s += ws[ci * 128 + hh * 64 + d] * a[hh * 64 + d];
        w0a[t] = s;
    }
    __syncthreads();
    const long row = (long)blockIdx.x * 16 + (t >> 4);
    const int c0 = (t & 15) * 8;
    const float x0 = x[row * 3 + 0], x1 = x[row * 3 + 1], x2 = x[row * 3 + 2];
    union { uint4 u; u16 s[8]; } o;
#pragma unroll
    for (int j = 0; j < 8; j++)
        o.s[j] = f2bf(x0 * ws[c0 + j] + x1 * ws[128 + c0 + j] + x2 * ws[256 + c0 + j]);
    *(uint4*)(h + row * 128 + c0) = o.u;
    if ((t & 15) < 4) {
        int j = t & 3;
        aux[row * 4 + j] = x0 * w0a[j] + x1 * w0a[4 + j] + x2 * w0a[8 + j];
    }
}

// ---------------- GAT MFMA GEMM (in-place): hbuf = hbuf @ W ; aux = fp32 dots
// r18: reverted to the r16 128-row shape (r17's 64-row split regressed 63->84us:
// 2x Wt L2 traffic + half the MFMA per barrier outweighed the occupancy gain).
// Added: ks=0 B-frag register prefetch issued BEFORE the staging barrier, so MFMA
// starts immediately after __syncthreads instead of stalling ~200cyc on L2.
__global__ __launch_bounds__(256) void k_gemm_gat(u16* __restrict__ HB,
                                                  const u16* __restrict__ Wt,
                                                  const float* __restrict__ a_src,
                                                  const float* __restrict__ a_dst,
                                                  float* __restrict__ aux) {
    __shared__ u16 ldsA[128 * 128];  // 32 KB
    __shared__ float avec[128], dvec[128];
    const int t = threadIdx.x;
    const int w = t >> 6, lane = t & 63;
    const int q = lane >> 4, col = lane & 15;
    const long bm = (long)blockIdx.x * 128;
    const int wm = w * 32;

    if (t < 128) avec[t] = a_src[t];
    else dvec[t - 128] = a_dst[t - 128];

#pragma unroll
    for (int i = 0; i < 8; i++) {
        const int slot = (w * 8 + i) * 64 + lane;
        const int r = slot >> 4, cs = slot & 15;
        const int cg = cs ^ (r & 15);
        async16(HB + (bm + r) * 128 + cg * 8, ldsA + (w * 8 + i) * 512);
    }
    // prefetch ks=0 B-frags while the async16 staging drains
    bf16x8 bf0[8];
#pragma unroll
    for (int nt = 0; nt < 8; nt++)
        bf0[nt] = *(const bf16x8*)&Wt[(nt * 16 + col) * 128 + q * 8];
    __syncthreads();

    f32x4 acc[2][8] = {};
#pragma unroll
    for (int ks = 0; ks < 4; ks++) {
        const int ck = ks * 4 + q;
        bf16x8 af[2];
#pragma unroll
        for (int mt = 0; mt < 2; mt++) {
            const int m = wm + mt * 16 + col;
            af[mt] = *(const bf16x8*)&ldsA[m * 128 + ((ck ^ (m & 15)) << 3)];
        }
#pragma unroll
        for (int nt = 0; nt < 8; nt++) {
            const bf16x8 bf = (ks == 0) ? bf0[nt]
                              : *(const bf16x8*)&Wt[(nt * 16 + col) * 128 + ck * 8];
            acc[0][nt] = __builtin_amdgcn_mfma_f32_16x16x32_bf16(af[0], bf, acc[0][nt], 0, 0, 0);
            acc[1][nt] = __builtin_amdgcn_mfma_f32_16x16x32_bf16(af[1], bf, acc[1][nt], 0, 0, 0);
        }
    }
    __syncthreads();
#pragma unroll
    for (int mt = 0; mt < 2; mt++) {
#pragma unroll
        for (int nt = 0; nt < 8; nt++) {
            const int cg = nt * 16 + col;
#pragma unroll
            for (int r = 0; r < 4; r++) {
                const long rg = bm + wm + mt * 16 + q * 4 + r;
                HB[rg * 128 + cg] = f2bf(acc[mt][nt][r]);
            }
        }
#pragma unroll
        for (int r = 0; r < 4; r++) {
            float s0 = 0.f, s1 = 0.f, d0 = 0.f, d1 = 0.f;
#pragma unroll
            for (int nt = 0; nt < 4; nt++) {
                const float v = acc[mt][nt][r];
                s0 += v * avec[nt * 16 + col];
                d0 += v * dvec[nt * 16 + col];
            }
#pragma unroll
            for (int nt = 4; nt < 8; nt++) {
                const float v = acc[mt][nt][r];
                s1 += v * avec[nt * 16 + col];
                d1 += v * dvec[nt * 16 + col];
            }
#pragma unroll
            for (int o = 1; o < 16; o <<= 1) {
                s0 += __shfl_xor(s0, o);
                s1 += __shfl_xor(s1, o);
                d0 += __shfl_xor(d0, o);
                d1 += __shfl_xor(d1, o);
            }
            if (col == 0) {
                const long rg = bm + wm + mt * 16 + q * 4 + r;
                aux[rg * 4 + 0] = s0;
                aux[rg * 4 + 1] = s1;
                aux[rg * 4 + 2] = d0;
                aux[rg * 4 + 3] = d1;
            }
        }
    }
}

// ---------------- GAT attention (4 graphs/block), 16B-vectorized staging + aggregation
#define GPB 4
__global__ __launch_bounds__(256) void k_gat_attn(u16* __restrict__ h,
                                                  const float* __restrict__ aux,
                                                  const float* __restrict__ bias,
                                                  const int* __restrict__ csr,
                                                  int relu_flag) {
    __shared__ __align__(16) u32 hs[GPB * Nn_ * 64];   // [g][n][cp]
    __shared__ float asd[GPB * Nn_ * 4];
    __shared__ float ev[GPB][162];
    __shared__ float mS[GPB][34], dS[GPB][34];
    __shared__ float bvec[128];
    __shared__ int srcS[Ee], dstS[Ee], offS[Nn_ + 1], eidS[Ee];
    const int t = threadIdx.x;
    const long g0 = (long)blockIdx.x * GPB;

    if (t < Ee) { srcS[t] = csr[t]; dstS[t] = csr[Ee + t]; eidS[t] = csr[180 + t]; }
    if (t >= 128 && t < 128 + Nn_ + 1) offS[t - 128] = csr[162 + t - 128];
    if (t < 128) bvec[t] = bias[t];
    {
        const uint4* hg4 = (const uint4*)((const u32*)h + g0 * 1088);
        for (int i = t; i < GPB * Nn_ * 16; i += 256) ((uint4*)hs)[i] = hg4[i];
        const float* ag = aux + g0 * 68;
        for (int i = t; i < GPB * Nn_ * 4; i += 256) asd[i] = ag[i];   // 272 > 256 (r8 bugfix)
    }
    __syncthreads();
    for (int i = t; i < GPB * 162; i += 256) {
        const int g = i / 162, rem = i % 162, e = rem >> 1, hh = rem & 1;
        float v = asd[(g * Nn_ + srcS[e]) * 4 + hh] + asd[(g * Nn_ + dstS[e]) * 4 + 2 + hh];
        ev[g][rem] = (v > 0.f) ? v : 0.2f * v;
    }
    __syncthreads();
    if (t < GPB * 34) {
        const int g = t / 34, rem = t % 34, n = rem >> 1, hh = rem & 1;
        const int p0 = offS[n], p1 = offS[n + 1];
        float m = -1e30f;
        for (int p = p0; p < p1; p++) m = fmaxf(m, ev[g][eidS[p] * 2 + hh]);
        float den = 0.f;
        for (int p = p0; p < p1; p++) den += expf(ev[g][eidS[p] * 2 + hh] - m);
        mS[g][rem] = m;
        dS[g][rem] = den;
    }
    __syncthreads();
    for (int i = t; i < GPB * 162; i += 256) {
        const int g = i / 162, rem = i % 162, e = rem >> 1, hh = rem & 1;
        const int n = dstS[e];
        ev[g][rem] = expf(ev[g][rem] - mS[g][n * 2 + hh]) / (dS[g][n * 2 + hh] + 1e-16f);
    }
    __syncthreads();
    // aggregation: items = (g, n, cq), each covers 8 bf16 columns (one uint4)
    uint4* hgo4 = (uint4*)((u32*)h + g0 * 1088);
    for (int i = t; i < GPB * Nn_ * 16; i += 256) {
        const int g = i / (Nn_ * 16), rem = i % (Nn_ * 16);
        const int n = rem >> 4, cq = rem & 15, hh = cq >> 3;
        const int p0 = offS[n], p1 = offS[n + 1];
        float a[8] = {};
        for (int p = p0; p < p1; p++) {
            const int e = eidS[p];
            const uint4 hv = ((const uint4*)hs)[(g * Nn_ + srcS[e]) * 16 + cq];
            const float al = ev[g][e * 2 + hh];
            a[0] += al * bflo(hv.x); a[1] += al * bfhi(hv.x);
            a[2] += al * bflo(hv.y); a[3] += al * bfhi(hv.y);
            a[4] += al * bflo(hv.z); a[5] += al * bfhi(hv.z);
            a[6] += al * bflo(hv.w); a[7] += al * bfhi(hv.w);
        }
        const int c0 = cq * 8;
#pragma unroll
        for (int m2 = 0; m2 < 8; m2++) {
            a[m2] += bvec[c0 + m2];
            if (relu_flag) a[m2] = fmaxf(a[m2], 0.f);
        }
        uint4 o;
        o.x = (u32)f2bf(a[0]) | ((u32)f2bf(a[1]) << 16);
        o.y = (u32)f2bf(a[2]) | ((u32)f2bf(a[3]) << 16);
        o.z = (u32)f2bf(a[4]) | ((u32)f2bf(a[5]) << 16);
        o.w = (u32)f2bf(a[6]) | ((u32)f2bf(a[7]) << 16);
        hgo4[(g * Nn_ + n) * 16 + cq] = o;
    }
}

// ---------------- bf16 MFMA GEMM: C[M,ldc] = A[M,K]bf16 @ Bt[N,K]bf16^T + b1[n]+b2[n] (fp32)
__global__ __launch_bounds__(256) void k_gemm_mfma(const u16* __restrict__ A,
                                                   const u16* __restrict__ Bt,
                                                   float* __restrict__ Cm,
                                                   const float* __restrict__ b1,
                                                   const float* __restrict__ b2,
                                                   int K, int ldc) {
    __shared__ u16 ldsA[128 * 64];
    __shared__ u16 ldsB[128 * 64];
    const int w = threadIdx.x >> 6;
    const int lane = threadIdx.x & 63;
    const long bm = (long)blockIdx.x * 128;
    const int bn = blockIdx.y * 128;
    const int wm = (w & 1) * 64, wn = (w >> 1) * 64;
    const int q = lane >> 4, col = lane & 15;
    f32x4 acc[4][4] = {};
    for (int k0 = 0; k0 < K; k0 += 64) {
#pragma unroll
        for (int i = 0; i < 4; i++) {
            const int slot = (w * 4 + i) * 64 + lane;
            const int r = slot >> 3, cs = slot & 7;
            const int cg = cs ^ (r & 7);
            async16(A + (bm + r) * (long)K + k0 + cg * 8, ldsA + (w * 4 + i) * 512);
            async16(Bt + (long)(bn + r) * K + k0 + cg * 8, ldsB + (w * 4 + i) * 512);
        }
        __syncthreads();
#pragma unroll
        for (int kk = 0; kk < 2; kk++) {
            bf16x8 af[4], bfr[4];
#pragma unroll
            for (int mt = 0; mt < 4; mt++) {
                const int m = wm + mt * 16 + col;
                const int cs = (kk * 4 + q) ^ (m & 7);
                af[mt] = *(const bf16x8*)&ldsA[m * 64 + cs * 8];
            }
#pragma unroll
            for (int nt = 0; nt < 4; nt++) {
                const int n = wn + nt * 16 + col;
                const int cs = (kk * 4 + q) ^ (n & 7);
                bfr[nt] = *(const bf16x8*)&ldsB[n * 64 + cs * 8];
            }
#pragma unroll
            for (int mt = 0; mt < 4; mt++)
#pragma unroll
                for (int nt = 0; nt < 4; nt++)
                    acc[mt][nt] = __builtin_amdgcn_mfma_f32_16x16x32_bf16(af[mt], bfr[nt], acc[mt][nt], 0, 0, 0);
        }
        __syncthreads();
    }
#pragma unroll
    for (int mt = 0; mt < 4; mt++)
#pragma unroll
        for (int nt = 0; nt < 4; nt++) {
            const int cg = bn + wn + nt * 16 + col;
            const float bb = b1[cg] + b2[cg];
#pragma unroll
            for (int r = 0; r < 4; r++) {
                const long rg = bm + wm + mt * 16 + q * 4 + r;
                Cm[rg * ldc + cg] = acc[mt][nt][r] + bb;
            }
        }
}

// ---------------- LSTM recurrence: f16 packed whh + v_dot2_f32_f16 MAC
template <int OBF16>
__global__ __launch_bounds__(512, 1) void k_lstm(const float* __restrict__ XW,
                                                 const u16* __restrict__ whhh,
                                                 void* __restrict__ hseq) {
    const int b = blockIdx.x, j = threadIdx.x;
    u32 wp[64];   // 128 f16 = 64 VGPRs (register-resident at this footprint)
    const u32* wrow = (const u32*)(whhh + (long)j * OUT_);
#pragma unroll
    for (int k = 0; k < 64; k++) wp[k] = wrow[k];
    __shared__ __align__(16) u16 h_sh[OUT_];   // packed f16 h-state (64 u32)
    __shared__ float gate_s[G4];
    float c_r = 0.f;
    if (j < 64) ((u32*)h_sh)[j] = 0;
    float xw = XW[((long)b * Tt + 0) * G4 + j];
    const int gate = j >> 7;   // 0:i 1:f 2:g 3:o
    __syncthreads();
    for (int t = 0; t < Tt; t++) {
        float xw_next = 0.f;
        if (t < Tt - 1) xw_next = XW[((long)b * Tt + t + 1) * G4 + j];
        float a0 = xw, a1 = 0.f, a2 = 0.f, a3 = 0.f;
        const uint4* hv4 = (const uint4*)h_sh;
#pragma unroll
        for (int k = 0; k < 4; k++) {
            const uint4 H0 = hv4[k], H1 = hv4[4 + k], H2 = hv4[8 + k], H3 = hv4[12 + k];
            a0 = dot2acc(wp[4 * k + 0], H0.x, a0);
            a0 = dot2acc(wp[4 * k + 1], H0.y, a0);
            a0 = dot2acc(wp[4 * k + 2], H0.z, a0);
            a0 = dot2acc(wp[4 * k + 3], H0.w, a0);
            a1 = dot2acc(wp[16 + 4 * k + 0], H1.x, a1);
            a1 = dot2acc(wp[16 + 4 * k + 1], H1.y, a1);
            a1 = dot2acc(wp[16 + 4 * k + 2], H1.z, a1);
            a1 = dot2acc(wp[16 + 4 * k + 3], H1.w, a1);
            a2 = dot2acc(wp[32 + 4 * k + 0], H2.x, a2);
            a2 = dot2acc(wp[32 + 4 * k + 1], H2.y, a2);
            a2 = dot2acc(wp[32 + 4 * k + 2], H2.z, a2);
            a2 = dot2acc(wp[32 + 4 * k + 3], H2.w, a2);
            a3 = dot2acc(wp[48 + 4 * k + 0], H3.x, a3);
            a3 = dot2acc(wp[48 + 4 * k + 1], H3.y, a3);
            a3 = dot2acc(wp[48 + 4 * k + 2], H3.z, a3);
            a3 = dot2acc(wp[48 + 4 * k + 3], H3.w, a3);
        }
        const float acc = (a0 + a1) + (a2 + a3);
        gate_s[j] = (gate == 2) ? tanhf(acc) : 1.f / (1.f + expf(-acc));
        __syncthreads();
        if (j < OUT_) {
            const float si = gate_s[j], sf = gate_s[OUT_ + j];
            const float gg = gate_s[2 * OUT_ + j], so = gate_s[3 * OUT_ + j];
            const float c = sf * c_r + si * gg;
            c_r = c;
            const float hh = so * tanhf(c);
            h_sh[j] = f2h(hh);
            const long idx = ((long)b * Tt + t) * OUT_ + j;
            if (OBF16) ((u16*)hseq)[idx] = f2bf(hh);
            else       ((float*)hseq)[idx] = hh;
        }
        xw = xw_next;
        __syncthreads();
    }
}

// ---------------- attention pooling + FC
__global__ __launch_bounds__(64) void k_attn_fc(const float* __restrict__ h2,
                                                const float* __restrict__ attn_w,
                                                const float* __restrict__ attn_b,
                                                const float* __restrict__ fc_w,
                                                const float* __restrict__ fc_b,
                                                float* __restrict__ out) {
    const int b = blockIdx.x, t = threadIdx.x;
    __shared__ float aw[Tt];
    __shared__ float ctx[OUT_];
    const float* hb = h2 + (long)b * Tt * OUT_;
    float acc = 0.f;
    for (int d = 0; d < OUT_; d++) acc += hb[t * OUT_ + d] * attn_w[d];
    float sc = tanhf(acc + attn_b[0]);
    float m = sc;
#pragma unroll
    for (int o = 32; o > 0; o >>= 1) m = fmaxf(m, __shfl_xor(m, o));
    float ex = expf(sc - m);
    float sum = ex;
#pragma unroll
    for (int o = 32; o > 0; o >>= 1) sum += __shfl_xor(sum, o);
    aw[t] = ex / sum;
    __syncthreads();
    for (int d = t; d < OUT_; d += 64) {
        float c = 0.f;
        for (int tt = 0; tt < Tt; tt++) c += aw[tt] * hb[tt * OUT_ + d];
        ctx[d] = c;
    }
    __syncthreads();
    if (t < NCLS) {
        float o = fc_b[t];
        for (int d = 0; d < OUT_; d++) o += ctx[d] * fc_w[t * OUT_ + d];
        out[b * NCLS + t] = o;
    }
}

extern "C" void kernel_launch(void* const* d_in, const int* in_sizes, int n_in,
                              void* d_out, int out_size, void* d_ws, size_t ws_size,
                              hipStream_t stream) {
    const float* x          = (const float*)d_in[0];
    const int*   edge_index = (const int*)d_in[1];
    const float* gw[4]  = {(const float*)d_in[2], (const float*)d_in[6], (const float*)d_in[10], (const float*)d_in[14]};
    const float* gas[4] = {(const float*)d_in[3], (const float*)d_in[7], (const float*)d_in[11], (const float*)d_in[15]};
    const float* gad[4] = {(const float*)d_in[4], (const float*)d_in[8], (const float*)d_in[12], (const float*)d_in[16]};
    const float* gb[4]  = {(const float*)d_in[5], (const float*)d_in[9], (const float*)d_in[13], (const float*)d_in[17]};
    const float* wih0 = (const float*)d_in[18];
    const float* whh0 = (const float*)d_in[19];
    const float* bih0 = (const float*)d_in[20];
    const float* bhh0 = (const float*)d_in[21];
    const float* wih1 = (const float*)d_in[22];
    const float* whh1 = (const float*)d_in[23];
    const float* bih1 = (const float*)d_in[24];
    const float* bhh1 = (const float*)d_in[25];
    const float* attn_w = (const float*)d_in[26];
    const float* attn_b = (const float*)d_in[27];
    const float* fc_w   = (const float*)d_in[28];
    const float* fc_b   = (const float*)d_in[29];
    float* out = (float*)d_out;
    char* p = (char*)d_ws;

    // Workspace (~158.2 MB; 176.2 MB proven OK in round 2)
    u16*   hbuf  = (u16*)(p + 0L);              // 71,303,168 B
    float* aux   = (float*)(p + 71303168L);     //  4,456,448 B
    float* XW0   = (float*)(p + 75759616L);     // 33,554,432 B
    float* XW1   = (float*)(p + 109314048L);    // 33,554,432 B
    float* h2s   = (float*)(p + 142868480L);    //  8,388,608 B
    u16*   h1s   = (u16*)(p + 151257088L);      //  4,194,304 B
    u16*   wih0b = (u16*)(p + 155451392L);      //  2,228,224 B
    u16*   wih1b = (u16*)(p + 157679616L);      //    131,072 B
    u16*   whh0h = (u16*)(p + 157810688L);      //    131,072 B  (f16)
    u16*   whh1h = (u16*)(p + 157941760L);      //    131,072 B  (f16)
    u16*   wt1   = (u16*)(p + 158072832L);      //     32,768 B (x3)
    u16*   wt2   = (u16*)(p + 158105600L);
    u16*   wt3   = (u16*)(p + 158138368L);
    int*   csr   = (int*)(p + 158171136L);      //      1,044 B

    k_setup<<<1, 128, 0, stream>>>(edge_index, csr);
    k_convert_small<<<960, 256, 0, stream>>>(gw[1], gw[2], gw[3], wih1, whh0, whh1,
                                             wt1, wt2, wt3, wih1b, whh0h, whh1h);
    k_convert<<<(512 * 2176 + 255) / 256, 256, 0, stream>>>(wih0, wih0b, 512L * 2176);

    // GAT layer 0 projection (+fp32 attn dots) then attention
    k_l0<<<Mg / 16, 256, 0, stream>>>(x, gw[0], gas[0], gad[0], hbuf, aux);
    k_gat_attn<<<Gg / GPB, 256, 0, stream>>>(hbuf, aux, gb[0], csr, 1);
    // layers 1..3: in-place MFMA GEMM (128-row blocks, r16 shape) + attention
    k_gemm_gat<<<Mg / 128, 256, 0, stream>>>(hbuf, wt1, gas[1], gad[1], aux);
    k_gat_attn<<<Gg / GPB, 256, 0, stream>>>(hbuf, aux, gb[1], csr, 0);
    k_gemm_gat<<<Mg / 128, 256, 0, stream>>>(hbuf, wt2, gas[2], gad[2], aux);
    k_gat_attn<<<Gg / GPB, 256, 0, stream>>>(hbuf, aux, gb[2], csr, 1);
    k_gemm_gat<<<Mg / 128, 256, 0, stream>>>(hbuf, wt3, gas[3], gad[3], aux);
    k_gat_attn<<<Gg / GPB, 256, 0, stream>>>(hbuf, aux, gb[3], csr, 0);

    // LSTM layer 0: input GEMM (hbuf == lstm_in [16384,2176] bf16) + dot2 recurrence
    k_gemm_mfma<<<dim3(Gg / 128, 4), 256, 0, stream>>>(hbuf, wih0b, XW0, bih0, bhh0, LSTM_IN, G4);
    k_lstm<1><<<Bb, 512, 0, stream>>>(XW0, whh0h, h1s);
    // LSTM layer 1
    k_gemm_mfma<<<dim3(Gg / 128, 4), 256, 0, stream>>>(h1s, wih1b, XW1, bih1, bhh1, OUT_, G4);
    k_lstm<0><<<Bb, 512, 0, stream>>>(XW1, whh1h, h2s);

    k_attn_fc<<<Bb, 64, 0, stream>>>(h2s, attn_w, attn_b, fc_w, fc_b, out);
}

// Round 19
// 660.245 us; speedup vs baseline: 1.1195x; 1.0090x over previous
//
#include <hip/hip_runtime.h>
#include <hip/hip_bf16.h>
#include <hip/hip_fp16.h>

// Problem constants
#define Bb 256
#define Nn_ 17
#define CIN 3
#define HID 64
#define CCH 128        // HEADS*HID
#define Gg 16384       // B*S
#define Ee 81          // 64 edges + 17 self loops
#define LSTM_IN 2176   // 17*128
#define OUT_ 128
#define G4 512         // 4*OUT
#define NCLS 10
#define Tt 64
#define Mg (Gg * Nn_)  // 278528

typedef unsigned short u16;
typedef unsigned int u32;
typedef __attribute__((ext_vector_type(8))) short bf16x8;
typedef __attribute__((ext_vector_type(4))) float f32x4;
typedef _Float16 h2f __attribute__((ext_vector_type(2)));

__device__ __forceinline__ u16 f2bf(float f) {   // RNE fp32->bf16
    u32 u = __float_as_uint(f);
    u += 0x7fffu + ((u >> 16) & 1u);
    return (u16)(u >> 16);
}
__device__ __forceinline__ float bflo(u32 v) { return __uint_as_float(v << 16); }
__device__ __forceinline__ float bfhi(u32 v) { return __uint_as_float(v & 0xffff0000u); }
__device__ __forceinline__ u16 f2h(float f) {    // RNE fp32->fp16
    _Float16 h = (_Float16)f;
    return *(u16*)&h;
}

// packed half2 dot-accumulate: acc += w.lo*h.lo + w.hi*h.hi
__device__ __forceinline__ float dot2acc(u32 w, u32 h, float acc) {
#if __has_builtin(__builtin_amdgcn_fdot2)
    return __builtin_amdgcn_fdot2(*(h2f*)&w, *(h2f*)&h, acc, false);
#else
    const __half2 wv = *(__half2*)&w, hv = *(__half2*)&h;
    return acc + __half2float(wv.x) * __half2float(hv.x)
               + __half2float(wv.y) * __half2float(hv.y);
#endif
}

__device__ __forceinline__ void async16(const void* g, void* l) {
    __builtin_amdgcn_global_load_lds((__attribute__((address_space(1))) u32*)g,
                                     (__attribute__((address_space(3))) u32*)l, 16, 0, 0);
}

// ---------------- setup: build src/dst + dst-CSR (parallel edge staging)
__global__ __launch_bounds__(128) void k_setup(const int* __restrict__ edge_index,
                                               int* __restrict__ csr) {
    __shared__ int eis[128];
    const int t = threadIdx.x;
    eis[t] = edge_index[t];
    __syncthreads();
    if (t == 0) {
        int* src = csr;                    // [81]
        int* dst = csr + Ee;               // [81]
        int* off = csr + 2 * Ee;           // [18]
        int* eid = csr + 2 * Ee + Nn_ + 1; // [81]
        int s_[Ee], d_[Ee];
        for (int e = 0; e < 64; e++) { s_[e] = eis[e]; d_[e] = eis[64 + e]; }
        for (int n = 0; n < Nn_; n++) { s_[64 + n] = n; d_[64 + n] = n; }
        int cnt[Nn_];
        for (int n = 0; n < Nn_; n++) cnt[n] = 0;
        for (int e = 0; e < Ee; e++) cnt[d_[e]]++;
        int offl[Nn_ + 1];
        offl[0] = 0;
        for (int n = 0; n < Nn_; n++) offl[n + 1] = offl[n] + cnt[n];
        int pos[Nn_];
        for (int n = 0; n < Nn_; n++) pos[n] = offl[n];
        for (int e = 0; e < Ee; e++) { src[e] = s_[e]; dst[e] = d_[e]; }
        for (int n = 0; n <= Nn_; n++) off[n] = offl[n];
        for (int e = 0; e < Ee; e++) eid[pos[d_[e]]++] = e;
    }
}

__global__ void k_convert(const float* __restrict__ in, u16* __restrict__ out, long n) {
    long i = (long)blockIdx.x * 256 + threadIdx.x;
    if (i < n) out[i] = f2bf(in[i]);
}

// ---------------- merged small-weight conversion: 3 transposed GAT weights (bf16),
// wih1 (bf16 for MFMA), whh0/whh1 (f16 for the dot2 recurrence)
__global__ __launch_bounds__(256) void k_convert_small(
    const float* __restrict__ gw1, const float* __restrict__ gw2, const float* __restrict__ gw3,
    const float* __restrict__ wih1, const float* __restrict__ whh0, const float* __restrict__ whh1,
    u16* __restrict__ wt1, u16* __restrict__ wt2, u16* __restrict__ wt3,
    u16* __restrict__ wih1b, u16* __restrict__ whh0h, u16* __restrict__ whh1h) {
    const int i = blockIdx.x * 256 + threadIdx.x;
    if (i < 49152) {
        const int which = i / 16384, r = i % 16384;
        const float* s = (which == 0) ? gw1 : (which == 1) ? gw2 : gw3;
        u16* d = (which == 0) ? wt1 : (which == 1) ? wt2 : wt3;
        const int n = r >> 7, k = r & 127;
        d[r] = f2bf(s[k * 128 + n]);
    } else {
        const int ii = i - 49152;
        const int which = ii / 65536, r = ii % 65536;
        if (which == 0) wih1b[r] = f2bf(wih1[r]);
        else if (which == 1) whh0h[r] = f2h(whh0[r]);
        else whh1h[r] = f2h(whh1[r]);
    }
}

// ---------------- GAT layer 0: h[Mg,128]=x@W0 (bf16) + aux[Mg,4]=x@(W0@a) (fp32)
__global__ __launch_bounds__(256) void k_l0(const float* __restrict__ x,
                                            const float* __restrict__ W0,
                                            const float* __restrict__ gas0,
                                            const float* __restrict__ gad0,
                                            u16* __restrict__ h, float* __restrict__ aux) {
    __shared__ float ws[3 * 128];
    __shared__ float w0a[12];   // [ci][j]  j: src_h0,src_h1,dst_h0,dst_h1
    const int t = threadIdx.x;
    for (int i = t; i < 384; i += 256) ws[i] = W0[i];
    __syncthreads();
    if (t < 12) {
        int ci = t >> 2, j = t & 3;
        const float* a = (j < 2) ? gas0 : gad0;
        int hh = j & 1;
        float s = 0.f;
        for (int d = 0; d < HID; d++) s += ws[ci * 128 + hh * 64 + d] * a[hh * 64 + d];
        w0a[t] = s;
    }
    __syncthreads();
    const long row = (long)blockIdx.x * 16 + (t >> 4);
    const int c0 = (t & 15) * 8;
    const float x0 = x[row * 3 + 0], x1 = x[row * 3 + 1], x2 = x[row * 3 + 2];
    union { uint4 u; u16 s[8]; } o;
#pragma unroll
    for (int j = 0; j < 8; j++)
        o.s[j] = f2bf(x0 * ws[c0 + j] + x1 * ws[128 + c0 + j] + x2 * ws[256 + c0 + j]);
    *(uint4*)(h + row * 128 + c0) = o.u;
    if ((t & 15) < 4) {
        int j = t & 3;
        aux[row * 4 + j] = x0 * w0a[j] + x1 * w0a[4 + j] + x2 * w0a[8 + j];
    }
}

// ---------------- GAT MFMA GEMM (in-place): hbuf = hbuf @ W ; aux = fp32 dots
// r16 128-row shape + r18 ks=0 B-frag prefetch (proven 57.5us).
__global__ __launch_bounds__(256) void k_gemm_gat(u16* __restrict__ HB,
                                                  const u16* __restrict__ Wt,
                                                  const float* __restrict__ a_src,
                                                  const float* __restrict__ a_dst,
                                                  float* __restrict__ aux) {
    __shared__ u16 ldsA[128 * 128];  // 32 KB
    __shared__ float avec[128], dvec[128];
    const int t = threadIdx.x;
    const int w = t >> 6, lane = t & 63;
    const int q = lane >> 4, col = lane & 15;
    const long bm = (long)blockIdx.x * 128;
    const int wm = w * 32;

    if (t < 128) avec[t] = a_src[t];
    else dvec[t - 128] = a_dst[t - 128];

#pragma unroll
    for (int i = 0; i < 8; i++) {
        const int slot = (w * 8 + i) * 64 + lane;
        const int r = slot >> 4, cs = slot & 15;
        const int cg = cs ^ (r & 15);
        async16(HB + (bm + r) * 128 + cg * 8, ldsA + (w * 8 + i) * 512);
    }
    // prefetch ks=0 B-frags while the async16 staging drains
    bf16x8 bf0[8];
#pragma unroll
    for (int nt = 0; nt < 8; nt++)
        bf0[nt] = *(const bf16x8*)&Wt[(nt * 16 + col) * 128 + q * 8];
    __syncthreads();

    f32x4 acc[2][8] = {};
#pragma unroll
    for (int ks = 0; ks < 4; ks++) {
        const int ck = ks * 4 + q;
        bf16x8 af[2];
#pragma unroll
        for (int mt = 0; mt < 2; mt++) {
            const int m = wm + mt * 16 + col;
            af[mt] = *(const bf16x8*)&ldsA[m * 128 + ((ck ^ (m & 15)) << 3)];
        }
#pragma unroll
        for (int nt = 0; nt < 8; nt++) {
            const bf16x8 bf = (ks == 0) ? bf0[nt]
                              : *(const bf16x8*)&Wt[(nt * 16 + col) * 128 + ck * 8];
            acc[0][nt] = __builtin_amdgcn_mfma_f32_16x16x32_bf16(af[0], bf, acc[0][nt], 0, 0, 0);
            acc[1][nt] = __builtin_amdgcn_mfma_f32_16x16x32_bf16(af[1], bf, acc[1][nt], 0, 0, 0);
        }
    }
    __syncthreads();
#pragma unroll
    for (int mt = 0; mt < 2; mt++) {
#pragma unroll
        for (int nt = 0; nt < 8; nt++) {
            const int cg = nt * 16 + col;
#pragma unroll
            for (int r = 0; r < 4; r++) {
                const long rg = bm + wm + mt * 16 + q * 4 + r;
                HB[rg * 128 + cg] = f2bf(acc[mt][nt][r]);
            }
        }
#pragma unroll
        for (int r = 0; r < 4; r++) {
            float s0 = 0.f, s1 = 0.f, d0 = 0.f, d1 = 0.f;
#pragma unroll
            for (int nt = 0; nt < 4; nt++) {
                const float v = acc[mt][nt][r];
                s0 += v * avec[nt * 16 + col];
                d0 += v * dvec[nt * 16 + col];
            }
#pragma unroll
            for (int nt = 4; nt < 8; nt++) {
                const float v = acc[mt][nt][r];
                s1 += v * avec[nt * 16 + col];
                d1 += v * dvec[nt * 16 + col];
            }
#pragma unroll
            for (int o = 1; o < 16; o <<= 1) {
                s0 += __shfl_xor(s0, o);
                s1 += __shfl_xor(s1, o);
                d0 += __shfl_xor(d0, o);
                d1 += __shfl_xor(d1, o);
            }
            if (col == 0) {
                const long rg = bm + wm + mt * 16 + q * 4 + r;
                aux[rg * 4 + 0] = s0;
                aux[rg * 4 + 1] = s1;
                aux[rg * 4 + 2] = d0;
                aux[rg * 4 + 3] = d1;
            }
        }
    }
}

// ---------------- GAT attention (4 graphs/block)
// r19: (a) hs staged via global_load_lds width=16 (wave-uniform base + lane*16; removes
// 1088 VGPR-roundtrip loads/block); (b) edge-score phase removed -- scores recomputed
// inline in max/den and alpha (bit-identical: 2 LDS reads + add + leaky per edge),
// cutting barriers 4->3 and dropping 648 LDS writes+reads; (c) dS holds 1/den.
#define GPB 4
__global__ __launch_bounds__(256) void k_gat_attn(u16* __restrict__ h,
                                                  const float* __restrict__ aux,
                                                  const float* __restrict__ bias,
                                                  const int* __restrict__ csr,
                                                  int relu_flag) {
    __shared__ __align__(16) u32 hs[GPB * Nn_ * 64];   // [g][n][cp], 17408 B
    __shared__ float asd[GPB * Nn_ * 4];
    __shared__ float ev[GPB][162];
    __shared__ float mS[GPB][34], dS[GPB][34];         // dS = 1/(den+eps)
    __shared__ float bvec[128];
    __shared__ int srcS[Ee], dstS[Ee], offS[Nn_ + 1], eidS[Ee];
    const int t = threadIdx.x;
    const int w = t >> 6, lane = t & 63;
    const long g0 = (long)blockIdx.x * GPB;

    if (t < Ee) { srcS[t] = csr[t]; dstS[t] = csr[Ee + t]; eidS[t] = csr[180 + t]; }
    if (t >= 128 && t < 128 + Nn_ + 1) offS[t - 128] = csr[162 + t - 128];
    if (t < 128) bvec[t] = bias[t];
    {
        const u32* hgp = (const u32*)h + g0 * 1088;
        // 1088 16B slots: 4 full passes + 64-slot tail on wave 0
#pragma unroll
        for (int i = 0; i < 4; i++) {
            const int slot = (i * 4 + w) * 64 + lane;
            async16(hgp + slot * 4, hs + slot * 4);
        }
        if (w == 0) {
            const int slot = 1024 + lane;
            async16(hgp + slot * 4, hs + slot * 4);
        }
        const float* ag = aux + g0 * 68;
        for (int i = t; i < GPB * Nn_ * 4; i += 256) asd[i] = ag[i];   // 272 > 256 (r8 bugfix)
    }
    __syncthreads();   // drains global_load_lds + asd writes
    // per-node max + inv-den, scores inline: 272 items
    for (int i = t; i < GPB * 34; i += 256) {
        const int g = i / 34, rem = i % 34, n = rem >> 1, hh = rem & 1;
        const int p0 = offS[n], p1 = offS[n + 1];
        float m = -1e30f;
        for (int p = p0; p < p1; p++) {
            const int e = eidS[p];
            float v = asd[(g * Nn_ + srcS[e]) * 4 + hh] + asd[(g * Nn_ + dstS[e]) * 4 + 2 + hh];
            v = (v > 0.f) ? v : 0.2f * v;
            m = fmaxf(m, v);
        }
        float den = 0.f;
        for (int p = p0; p < p1; p++) {
            const int e = eidS[p];
            float v = asd[(g * Nn_ + srcS[e]) * 4 + hh] + asd[(g * Nn_ + dstS[e]) * 4 + 2 + hh];
            v = (v > 0.f) ? v : 0.2f * v;
            den += expf(v - m);
        }
        mS[g][rem] = m;
        dS[g][rem] = 1.f / (den + 1e-16f);
    }
    __syncthreads();
    // alpha, scores inline: 648 items
    for (int i = t; i < GPB * 162; i += 256) {
        const int g = i / 162, rem = i % 162, e = rem >> 1, hh = rem & 1;
        float v = asd[(g * Nn_ + srcS[e]) * 4 + hh] + asd[(g * Nn_ + dstS[e]) * 4 + 2 + hh];
        v = (v > 0.f) ? v : 0.2f * v;
        const int n = dstS[e];
        ev[g][rem] = expf(v - mS[g][n * 2 + hh]) * dS[g][n * 2 + hh];
    }
    __syncthreads();
    // aggregation: items = (g, n, cq), each covers 8 bf16 columns (one uint4)
    uint4* hgo4 = (uint4*)((u32*)h + g0 * 1088);
    for (int i = t; i < GPB * Nn_ * 16; i += 256) {
        const int g = i / (Nn_ * 16), rem = i % (Nn_ * 16);
        const int n = rem >> 4, cq = rem & 15, hh = cq >> 3;
        const int p0 = offS[n], p1 = offS[n + 1];
        float a[8] = {};
        for (int p = p0; p < p1; p++) {
            const int e = eidS[p];
            const uint4 hv = ((const uint4*)hs)[(g * Nn_ + srcS[e]) * 16 + cq];
            const float al = ev[g][e * 2 + hh];
            a[0] += al * bflo(hv.x); a[1] += al * bfhi(hv.x);
            a[2] += al * bflo(hv.y); a[3] += al * bfhi(hv.y);
            a[4] += al * bflo(hv.z); a[5] += al * bfhi(hv.z);
            a[6] += al * bflo(hv.w); a[7] += al * bfhi(hv.w);
        }
        const int c0 = cq * 8;
#pragma unroll
        for (int m2 = 0; m2 < 8; m2++) {
            a[m2] += bvec[c0 + m2];
            if (relu_flag) a[m2] = fmaxf(a[m2], 0.f);
        }
        uint4 o;
        o.x = (u32)f2bf(a[0]) | ((u32)f2bf(a[1]) << 16);
        o.y = (u32)f2bf(a[2]) | ((u32)f2bf(a[3]) << 16);
        o.z = (u32)f2bf(a[4]) | ((u32)f2bf(a[5]) << 16);
        o.w = (u32)f2bf(a[6]) | ((u32)f2bf(a[7]) << 16);
        hgo4[(g * Nn_ + n) * 16 + cq] = o;
    }
}

// ---------------- bf16 MFMA GEMM: C[M,ldc] = A[M,K]bf16 @ Bt[N,K]bf16^T + b1[n]+b2[n] (fp32)
__global__ __launch_bounds__(256) void k_gemm_mfma(const u16* __restrict__ A,
                                                   const u16* __restrict__ Bt,
                                                   float* __restrict__ Cm,
                                                   const float* __restrict__ b1,
                                                   const float* __restrict__ b2,
                                                   int K, int ldc) {
    __shared__ u16 ldsA[128 * 64];
    __shared__ u16 ldsB[128 * 64];
    const int w = threadIdx.x >> 6;
    const int lane = threadIdx.x & 63;
    const long bm = (long)blockIdx.x * 128;
    const int bn = blockIdx.y * 128;
    const int wm = (w & 1) * 64, wn = (w >> 1) * 64;
    const int q = lane >> 4, col = lane & 15;
    f32x4 acc[4][4] = {};
    for (int k0 = 0; k0 < K; k0 += 64) {
#pragma unroll
        for (int i = 0; i < 4; i++) {
            const int slot = (w * 4 + i) * 64 + lane;
            const int r = slot >> 3, cs = slot & 7;
            const int cg = cs ^ (r & 7);
            async16(A + (bm + r) * (long)K + k0 + cg * 8, ldsA + (w * 4 + i) * 512);
            async16(Bt + (long)(bn + r) * K + k0 + cg * 8, ldsB + (w * 4 + i) * 512);
        }
        __syncthreads();
#pragma unroll
        for (int kk = 0; kk < 2; kk++) {
            bf16x8 af[4], bfr[4];
#pragma unroll
            for (int mt = 0; mt < 4; mt++) {
                const int m = wm + mt * 16 + col;
                const int cs = (kk * 4 + q) ^ (m & 7);
                af[mt] = *(const bf16x8*)&ldsA[m * 64 + cs * 8];
            }
#pragma unroll
            for (int nt = 0; nt < 4; nt++) {
                const int n = wn + nt * 16 + col;
                const int cs = (kk * 4 + q) ^ (n & 7);
                bfr[nt] = *(const bf16x8*)&ldsB[n * 64 + cs * 8];
            }
#pragma unroll
            for (int mt = 0; mt < 4; mt++)
#pragma unroll
                for (int nt = 0; nt < 4; nt++)
                    acc[mt][nt] = __builtin_amdgcn_mfma_f32_16x16x32_bf16(af[mt], bfr[nt], acc[mt][nt], 0, 0, 0);
        }
        __syncthreads();
    }
#pragma unroll
    for (int mt = 0; mt < 4; mt++)
#pragma unroll
        for (int nt = 0; nt < 4; nt++) {
            const int cg = bn + wn + nt * 16 + col;
            const float bb = b1[cg] + b2[cg];
#pragma unroll
            for (int r = 0; r < 4; r++) {
                const long rg = bm + wm + mt * 16 + q * 4 + r;
                Cm[rg * ldc + cg] = acc[mt][nt][r] + bb;
            }
        }
}

// ---------------- LSTM recurrence: f16 packed whh + v_dot2_f32_f16 MAC
template <int OBF16>
__global__ __launch_bounds__(512, 1) void k_lstm(const float* __restrict__ XW,
                                                 const u16* __restrict__ whhh,
                                                 void* __restrict__ hseq) {
    const int b = blockIdx.x, j = threadIdx.x;
    u32 wp[64];   // 128 f16 = 64 VGPRs (register-resident at this footprint)
    const u32* wrow = (const u32*)(whhh + (long)j * OUT_);
#pragma unroll
    for (int k = 0; k < 64; k++) wp[k] = wrow[k];
    __shared__ __align__(16) u16 h_sh[OUT_];   // packed f16 h-state (64 u32)
    __shared__ float gate_s[G4];
    float c_r = 0.f;
    if (j < 64) ((u32*)h_sh)[j] = 0;
    float xw = XW[((long)b * Tt + 0) * G4 + j];
    const int gate = j >> 7;   // 0:i 1:f 2:g 3:o
    __syncthreads();
    for (int t = 0; t < Tt; t++) {
        // branchless clamped prefetch (same address at final iter)
        const int tn = (t < Tt - 1) ? t + 1 : t;
        const float xw_next = XW[((long)b * Tt + tn) * G4 + j];
        float a0 = xw, a1 = 0.f, a2 = 0.f, a3 = 0.f;
        const uint4* hv4 = (const uint4*)h_sh;
#pragma unroll
        for (int k = 0; k < 4; k++) {
            const uint4 H0 = hv4[k], H1 = hv4[4 + k], H2 = hv4[8 + k], H3 = hv4[12 + k];
            a0 = dot2acc(wp[4 * k + 0], H0.x, a0);
            a0 = dot2acc(wp[4 * k + 1], H0.y, a0);
            a0 = dot2acc(wp[4 * k + 2], H0.z, a0);
            a0 = dot2acc(wp[4 * k + 3], H0.w, a0);
            a1 = dot2acc(wp[16 + 4 * k + 0], H1.x, a1);
            a1 = dot2acc(wp[16 + 4 * k + 1], H1.y, a1);
            a1 = dot2acc(wp[16 + 4 * k + 2], H1.z, a1);
            a1 = dot2acc(wp[16 + 4 * k + 3], H1.w, a1);
            a2 = dot2acc(wp[32 + 4 * k + 0], H2.x, a2);
            a2 = dot2acc(wp[32 + 4 * k + 1], H2.y, a2);
            a2 = dot2acc(wp[32 + 4 * k + 2], H2.z, a2);
            a2 = dot2acc(wp[32 + 4 * k + 3], H2.w, a2);
            a3 = dot2acc(wp[48 + 4 * k + 0], H3.x, a3);
            a3 = dot2acc(wp[48 + 4 * k + 1], H3.y, a3);
            a3 = dot2acc(wp[48 + 4 * k + 2], H3.z, a3);
            a3 = dot2acc(wp[48 + 4 * k + 3], H3.w, a3);
        }
        const float acc = (a0 + a1) + (a2 + a3);
        gate_s[j] = (gate == 2) ? tanhf(acc) : 1.f / (1.f + expf(-acc));
        __syncthreads();
        if (j < OUT_) {
            const float si = gate_s[j], sf = gate_s[OUT_ + j];
            const float gg = gate_s[2 * OUT_ + j], so = gate_s[3 * OUT_ + j];
            const float c = sf * c_r + si * gg;
            c_r = c;
            const float hh = so * tanhf(c);
            h_sh[j] = f2h(hh);
            const long idx = ((long)b * Tt + t) * OUT_ + j;
            if (OBF16) ((u16*)hseq)[idx] = f2bf(hh);
            else       ((float*)hseq)[idx] = hh;
        }
        xw = xw_next;
        __syncthreads();
    }
}

// ---------------- attention pooling + FC
__global__ __launch_bounds__(64) void k_attn_fc(const float* __restrict__ h2,
                                                const float* __restrict__ attn_w,
                                                const float* __restrict__ attn_b,
                                                const float* __restrict__ fc_w,
                                                const float* __restrict__ fc_b,
                                                float* __restrict__ out) {
    const int b = blockIdx.x, t = threadIdx.x;
    __shared__ float aw[Tt];
    __shared__ float ctx[OUT_];
    const float* hb = h2 + (long)b * Tt * OUT_;
    float acc = 0.f;
    for (int d = 0; d < OUT_; d++) acc += hb[t * OUT_ + d] * attn_w[d];
    float sc = tanhf(acc + attn_b[0]);
    float m = sc;
#pragma unroll
    for (int o = 32; o > 0; o >>= 1) m = fmaxf(m, __shfl_xor(m, o));
    float ex = expf(sc - m);
    float sum = ex;
#pragma unroll
    for (int o = 32; o > 0; o >>= 1) sum += __shfl_xor(sum, o);
    aw[t] = ex / sum;
    __syncthreads();
    for (int d = t; d < OUT_; d += 64) {
        float c = 0.f;
        for (int tt = 0; tt < Tt; tt++) c += aw[tt] * hb[tt * OUT_ + d];
        ctx[d] = c;
    }
    __syncthreads();
    if (t < NCLS) {
        float o = fc_b[t];
        for (int d = 0; d < OUT_; d++) o += ctx[d] * fc_w[t * OUT_ + d];
        out[b * NCLS + t] = o;
    }
}

extern "C" void kernel_launch(void* const* d_in, const int* in_sizes, int n_in,
                              void* d_out, int out_size, void* d_ws, size_t ws_size,
                              hipStream_t stream) {
    const float* x          = (const float*)d_in[0];
    const int*   edge_index = (const int*)d_in[1];
    const float* gw[4]  = {(const float*)d_in[2], (const float*)d_in[6], (const float*)d_in[10], (const float*)d_in[14]};
    const float* gas[4] = {(const float*)d_in[3], (const float*)d_in[7], (const float*)d_in[11], (const float*)d_in[15]};
    const float* gad[4] = {(const float*)d_in[4], (const float*)d_in[8], (const float*)d_in[12], (const float*)d_in[16]};
    const float* gb[4]  = {(const float*)d_in[5], (const float*)d_in[9], (const float*)d_in[13], (const float*)d_in[17]};
    const float* wih0 = (const float*)d_in[18];
    const float* whh0 = (const float*)d_in[19];
    const float* bih0 = (const float*)d_in[20];
    const float* bhh0 = (const float*)d_in[21];
    const float* wih1 = (const float*)d_in[22];
    const float* whh1 = (const float*)d_in[23];
    const float* bih1 = (const float*)d_in[24];
    const float* bhh1 = (const float*)d_in[25];
    const float* attn_w = (const float*)d_in[26];
    const float* attn_b = (const float*)d_in[27];
    const float* fc_w   = (const float*)d_in[28];
    const float* fc_b   = (const float*)d_in[29];
    float* out = (float*)d_out;
    char* p = (char*)d_ws;

    // Workspace (~158.2 MB; 176.2 MB proven OK in round 2)
    u16*   hbuf  = (u16*)(p + 0L);              // 71,303,168 B
    float* aux   = (float*)(p + 71303168L);     //  4,456,448 B
    float* XW0   = (float*)(p + 75759616L);     // 33,554,432 B
    float* XW1   = (float*)(p + 109314048L);    // 33,554,432 B
    float* h2s   = (float*)(p + 142868480L);    //  8,388,608 B
    u16*   h1s   = (u16*)(p + 151257088L);      //  4,194,304 B
    u16*   wih0b = (u16*)(p + 155451392L);      //  2,228,224 B
    u16*   wih1b = (u16*)(p + 157679616L);      //    131,072 B
    u16*   whh0h = (u16*)(p + 157810688L);      //    131,072 B  (f16)
    u16*   whh1h = (u16*)(p + 157941760L);      //    131,072 B  (f16)
    u16*   wt1   = (u16*)(p + 158072832L);      //     32,768 B (x3)
    u16*   wt2   = (u16*)(p + 158105600L);
    u16*   wt3   = (u16*)(p + 158138368L);
    int*   csr   = (int*)(p + 158171136L);      //      1,044 B

    k_setup<<<1, 128, 0, stream>>>(edge_index, csr);
    k_convert_small<<<960, 256, 0, stream>>>(gw[1], gw[2], gw[3], wih1, whh0, whh1,
                                             wt1, wt2, wt3, wih1b, whh0h, whh1h);
    k_convert<<<(512 * 2176 + 255) / 256, 256, 0, stream>>>(wih0, wih0b, 512L * 2176);

    // GAT layer 0 projection (+fp32 attn dots) then attention
    k_l0<<<Mg / 16, 256, 0, stream>>>(x, gw[0], gas[0], gad[0], hbuf, aux);
    k_gat_attn<<<Gg / GPB, 256, 0, stream>>>(hbuf, aux, gb[0], csr, 1);
    // layers 1..3: in-place MFMA GEMM (128-row blocks) + attention
    k_gemm_gat<<<Mg / 128, 256, 0, stream>>>(hbuf, wt1, gas[1], gad[1], aux);
    k_gat_attn<<<Gg / GPB, 256, 0, stream>>>(hbuf, aux, gb[1], csr, 0);
    k_gemm_gat<<<Mg / 128, 256, 0, stream>>>(hbuf, wt2, gas[2], gad[2], aux);
    k_gat_attn<<<Gg / GPB, 256, 0, stream>>>(hbuf, aux, gb[2], csr, 1);
    k_gemm_gat<<<Mg / 128, 256, 0, stream>>>(hbuf, wt3, gas[3], gad[3], aux);
    k_gat_attn<<<Gg / GPB, 256, 0, stream>>>(hbuf, aux, gb[3], csr, 0);

    // LSTM layer 0: input GEMM (hbuf == lstm_in [16384,2176] bf16) + dot2 recurrence
    k_gemm_mfma<<<dim3(Gg / 128, 4), 256, 0, stream>>>(hbuf, wih0b, XW0, bih0, bhh0, LSTM_IN, G4);
    k_lstm<1><<<Bb, 512, 0, stream>>>(XW0, whh0h, h1s);
    // LSTM layer 1
    k_gemm_mfma<<<dim3(Gg / 128, 4), 256, 0, stream>>>(h1s, wih1b, XW1, bih1, bhh1, OUT_, G4);
    k_lstm<0><<<Bb, 512, 0, stream>>>(XW1, whh1h, h2s);

    k_attn_fc<<<Bb, 64, 0, stream>>>(h2s, attn_w, attn_b, fc_w, fc_b, out);
}